// Round 2
// baseline (537.155 us; speedup 1.0000x reference)
//
#include <hip/hip_runtime.h>

// VentralModel: log-polar Gaussian pooling over steerable-pyramid moduli.
// Inputs (dict order): image(512*512), pyr0(4,512,512,2), win0(300,512,512),
//                      pyr1(4,256,256,2), win1(300,256,256),
//                      pyr2(4,128,128,2), win2(300,128,128),
//                      pyr3(4,64,64,2),   win3(300,64,64)
// Output: 4 scales x (4 ori x 300 win) + 300 mean_lum = 5100 fp32.
//
// Memory-bound on streaming the dense windows (~418 MB). Strategy: each block
// owns (scale, pixel-chunk of 2048, window-group of 100); moduli live in
// registers, windows streamed once; wave butterfly-reduce -> per-wave LDS
// slots -> one global atomicAdd pass per block into a 25 KB accumulator.

#define THREADS 256
#define PPT 8                 // pixels per thread
#define CHUNK (THREADS * PPT) // 2048 pixels per block
#define WPG 100               // windows per group (3 groups x 100 = 300)
#define N_WIN 300
#define ZTHRESH 1e-20f

// ws float layout:
//   [0,4800)    sums[s][o][w]  (s*1200 + o*300 + w)
//   [4800,6000) cnt[s][w]      (4800 + s*300 + w)
//   [6000,6300) imgsum[w]
#define WS_FLOATS 6300

template <bool HAS_IMG>
__device__ __forceinline__ void pool_scale(const float* __restrict__ pyr,
                                           const float* __restrict__ win,
                                           const float* __restrict__ img,
                                           float* __restrict__ ws,
                                           int HW, int scale, int chunk, int wgrp)
{
    __shared__ float lacc[4][WPG * 6];   // per-wave slots, no LDS atomics
    const int tid  = threadIdx.x;
    const int lane = tid & 63;
    const int wave = tid >> 6;

    const size_t pix0 = (size_t)chunk * CHUNK + (size_t)tid * PPT;

    // ---- load pyramid coeffs, compute moduli into registers (m[px][ori]) ----
    float m[PPT][4];
#pragma unroll
    for (int o = 0; o < 4; ++o) {
        const float4* pp = (const float4*)(pyr + ((size_t)o * HW + pix0) * 2);
#pragma unroll
        for (int j = 0; j < PPT / 2; ++j) {   // one float4 = 2 pixels (re,im,re,im)
            float4 v = pp[j];
            m[2 * j][o]     = sqrtf(fmaf(v.x, v.x, v.y * v.y));
            m[2 * j + 1][o] = sqrtf(fmaf(v.z, v.z, v.w * v.w));
        }
    }
    float iv[PPT];
    if (HAS_IMG) {
        const float4* ip = (const float4*)(img + pix0);
#pragma unroll
        for (int j = 0; j < PPT / 4; ++j) {
            float4 v = ip[j];
            iv[4 * j] = v.x; iv[4 * j + 1] = v.y; iv[4 * j + 2] = v.z; iv[4 * j + 3] = v.w;
        }
    }

    const int w0 = wgrp * WPG;

    // ---- stream windows ----
    for (int wi = 0; wi < WPG; ++wi) {
        const int w = w0 + wi;
        const float4* wp = (const float4*)(win + (size_t)w * HW + pix0);
        float wv[PPT];
#pragma unroll
        for (int j = 0; j < PPT / 4; ++j) {
            float4 v = wp[j];
            wv[4 * j] = v.x; wv[4 * j + 1] = v.y; wv[4 * j + 2] = v.z; wv[4 * j + 3] = v.w;
        }
        float a0 = 0.f, a1 = 0.f, a2 = 0.f, a3 = 0.f, ct = 0.f, ia = 0.f;
#pragma unroll
        for (int p = 0; p < PPT; ++p) {
            a0 = fmaf(wv[p], m[p][0], a0);
            a1 = fmaf(wv[p], m[p][1], a1);
            a2 = fmaf(wv[p], m[p][2], a2);
            a3 = fmaf(wv[p], m[p][3], a3);
            ct += (wv[p] > ZTHRESH) ? 1.f : 0.f;
            if (HAS_IMG) ia = fmaf(wv[p], iv[p], ia);
        }
        // wave-64 butterfly reduce
#pragma unroll
        for (int s = 1; s < 64; s <<= 1) {
            a0 += __shfl_xor(a0, s, 64);
            a1 += __shfl_xor(a1, s, 64);
            a2 += __shfl_xor(a2, s, 64);
            a3 += __shfl_xor(a3, s, 64);
            ct += __shfl_xor(ct, s, 64);
            if (HAS_IMG) ia += __shfl_xor(ia, s, 64);
        }
        if (lane == 0) {
            float* slot = &lacc[wave][wi * 6];
            slot[0] = a0; slot[1] = a1; slot[2] = a2; slot[3] = a3;
            slot[4] = ct; slot[5] = HAS_IMG ? ia : 0.f;
        }
    }
    __syncthreads();

    // ---- block flush: sum 4 waves, one global atomicAdd per value ----
    float* sums = ws + (size_t)scale * 1200;
    float* cnt  = ws + 4800 + (size_t)scale * 300;
    float* imgs = ws + 6000;
    for (int i = tid; i < WPG * 6; i += THREADS) {
        float v = lacc[0][i] + lacc[1][i] + lacc[2][i] + lacc[3][i];
        int wi = i / 6, f = i - wi * 6;
        int w = w0 + wi;
        if (f < 4) {
            atomicAdd(&sums[f * 300 + w], v);
        } else if (f == 4) {
            atomicAdd(&cnt[w], v);
        } else if (HAS_IMG) {
            atomicAdd(&imgs[w], v);
        }
    }
}

// grid layout: s0: 128 chunks x 3 wgrps = 384 | s1: 32x3=96 | s2: 8x3=24 | s3: 2x3=6
// total 510 blocks
__global__ __launch_bounds__(THREADS)
void pool_kernel(const float* __restrict__ image,
                 const float* __restrict__ pyr0, const float* __restrict__ win0,
                 const float* __restrict__ pyr1, const float* __restrict__ win1,
                 const float* __restrict__ pyr2, const float* __restrict__ win2,
                 const float* __restrict__ pyr3, const float* __restrict__ win3,
                 float* __restrict__ ws)
{
    int bid = blockIdx.x;
    if (bid < 384) {
        int chunk = bid & 127, wgrp = bid >> 7;
        pool_scale<true>(pyr0, win0, image, ws, 512 * 512, 0, chunk, wgrp);
    } else if (bid < 480) {
        int l = bid - 384;
        int chunk = l & 31, wgrp = l >> 5;
        pool_scale<false>(pyr1, win1, nullptr, ws, 256 * 256, 1, chunk, wgrp);
    } else if (bid < 504) {
        int l = bid - 480;
        int chunk = l & 7, wgrp = l >> 3;
        pool_scale<false>(pyr2, win2, nullptr, ws, 128 * 128, 2, chunk, wgrp);
    } else {
        int l = bid - 504;
        int chunk = l & 1, wgrp = l >> 1;
        pool_scale<false>(pyr3, win3, nullptr, ws, 64 * 64, 3, chunk, wgrp);
    }
}

__global__ __launch_bounds__(THREADS)
void finalize_kernel(const float* __restrict__ ws, float* __restrict__ out)
{
    int i = blockIdx.x * blockDim.x + threadIdx.x;
    if (i >= 5100) return;
    float v;
    if (i < 4800) {
        int s = i / 1200;
        int w = i % 300;
        v = ws[i] / ws[4800 + s * 300 + w];        // sums[s][o][w] / cnt[s][w]
    } else {
        int w = i - 4800;
        v = ws[6000 + w] / ws[4800 + w];           // imgsum[w] / cnt[0][w]
    }
    out[i] = v;
}

extern "C" void kernel_launch(void* const* d_in, const int* in_sizes, int n_in,
                              void* d_out, int out_size, void* d_ws, size_t ws_size,
                              hipStream_t stream)
{
    const float* image = (const float*)d_in[0];
    const float* pyr0  = (const float*)d_in[1];
    const float* win0  = (const float*)d_in[2];
    const float* pyr1  = (const float*)d_in[3];
    const float* win1  = (const float*)d_in[4];
    const float* pyr2  = (const float*)d_in[5];
    const float* win2  = (const float*)d_in[6];
    const float* pyr3  = (const float*)d_in[7];
    const float* win3  = (const float*)d_in[8];
    float* ws  = (float*)d_ws;
    float* out = (float*)d_out;

    hipMemsetAsync(d_ws, 0, WS_FLOATS * sizeof(float), stream);
    pool_kernel<<<510, THREADS, 0, stream>>>(image, pyr0, win0, pyr1, win1,
                                             pyr2, win2, pyr3, win3, ws);
    finalize_kernel<<<(5100 + THREADS - 1) / THREADS, THREADS, 0, stream>>>(ws, out);
}